// Round 15
// baseline (106.814 us; speedup 1.0000x reference)
//
#include <hip/hip_runtime.h>

typedef __bf16 bf16x8 __attribute__((ext_vector_type(8)));
typedef float f32x4 __attribute__((ext_vector_type(4)));

#define TWO_LOG2E 2.88539008177792681f   // 2*log2(e): exp(2x) = exp2(x*TWO_LOG2E)

#define GLOADLDS16(g, l) __builtin_amdgcn_global_load_lds(                     \
    (const __attribute__((address_space(1))) void*)(g),                        \
    (__attribute__((address_space(3))) void*)(l), 16, 0, 0)

__device__ __forceinline__ unsigned f2bf(float f) {
    unsigned u = __float_as_uint(f);
    return (u + 0x7FFFu + ((u >> 16) & 1u)) >> 16;   // RNE
}

// ---------------- kernel 1: row-normalize z=[z1;z2] -> bf16 zn[8192][256] ---------------
// Blocks 0..31 also zero S[8192]; block 32 zeroes out[0]. (R10-proven form.)
__global__ void __launch_bounds__(256) normalize_kernel(
    const float* __restrict__ z1, const float* __restrict__ z2,
    unsigned short* __restrict__ zn, float* __restrict__ S, float* __restrict__ out)
{
    if (blockIdx.x < 32) S[(blockIdx.x << 8) + threadIdx.x] = 0.f;
    if (blockIdx.x == 32 && threadIdx.x == 0) out[0] = 0.f;

    const int wave = threadIdx.x >> 6, lane = threadIdx.x & 63;
    const int row = (blockIdx.x << 2) + wave;               // 2048 blocks * 4 rows
    const float* src = (row < 4096) ? (z1 + row * 256) : (z2 + (row - 4096) * 256);
    float4 v = ((const float4*)src)[lane];                  // 64 lanes * 4 = 256
    float ss = v.x * v.x + v.y * v.y + v.z * v.z + v.w * v.w;
#pragma unroll
    for (int m = 32; m > 0; m >>= 1) ss += __shfl_xor(ss, m, 64);
    float sc = 1.0f / fmaxf(sqrtf(ss), 1e-8f);
    uint2 w;
    w.x = f2bf(v.x * sc) | (f2bf(v.y * sc) << 16);
    w.y = f2bf(v.z * sc) | (f2bf(v.w * sc) << 16);
    *(uint2*)(zn + row * 256 + (lane << 2)) = w;
}

// ---------------- kernel 2: barrier-free wave-autonomous sim-exp, 2KB chunks ------------
// R14's proven ordering discipline, one change: chunk shrunk to 32 cols x 32 k = 2KB,
// ring of FOUR 2KB buffers = 8KB LDS/block. LDS cap rises 10 -> 20 blocks/CU, register
// cap (124 VGPR -> 16 waves/CU) now binds: 4 waves/SIMD (was 2.5) => 2x latency hiding.
// Stage = 2 load instrs; steady-state `s_waitcnt vmcnt(6)` (= 3 stages in flight) orders
// global_load_lds DMA -> ds_read (compiler does NOT model it — R9's NaN); peeled tail
// drains 6->4->2->0. Ring index = chunk&3 (3 in flight never collide with consumee).
// No __syncthreads; no completion gate (R12/R13: core dump).
__global__ void __launch_bounds__(64, 2) simexp_kernel(
    const unsigned short* __restrict__ zn, float* __restrict__ S)
{
    __shared__ __align__(16) unsigned short Bs[4][1024];    // 4 x 2 KB ring, wave-private

    const int lane = threadIdx.x;
    const int q = lane >> 4, n16 = lane & 15;
    const int job = blockIdx.x;                 // 0..2047
    const int rowBase = (job >> 4) << 6;        // strip * 64
    const int colRun  = (job & 15) << 9;        // run * 512

    // A: 64 rows x K=256 in registers (frag: row=n16, k=q*8 within 32-elem step)
    bf16x8 a[4][8];
#pragma unroll
    for (int rt = 0; rt < 4; ++rt)
#pragma unroll
        for (int ks = 0; ks < 8; ++ks)
            a[rt][ks] = *(const bf16x8*)(zn + ((rowBase + (rt << 4) + n16) << 8)
                                            + (ks << 5) + (q << 3));

    // stage chunk m (col-chunk m>>3, k-chunk m&7): 32 cols x 32 k = 2KB, 2 loads.
    // slot s (16B): col c=s>>2, dest-within-col d=s&3, source k8 = d ^ (c&3) (swizzle)
    auto stage = [&](int m) {
        const int colBase = colRun + ((m >> 3) << 5);
        const int koff = (m & 7) << 5;          // elems
        unsigned short* base = (unsigned short*)&Bs[0][0] + ((m & 3) << 10);
#pragma unroll
        for (int p = 0; p < 2; ++p) {
            int s = (p << 6) + lane;            // 16B slot 0..127
            int c = s >> 2, d = s & 3;
            int k8 = d ^ (c & 3);
            GLOADLDS16(zn + ((colBase + c) << 8) + koff + (k8 << 3), base + (s << 3));
        }
    };

    float rs[4][4];
#pragma unroll
    for (int i = 0; i < 4; ++i)
#pragma unroll
        for (int j = 0; j < 4; ++j) rs[i][j] = 0.f;

    // consume chunk m (one 32-k step): 2 ds_read_b128 + 8 MFMA, a-step = m&7
    f32x4 acc[4][2];
    auto consume = [&](int m) {
        const unsigned short* bb = (const unsigned short*)&Bs[0][0] + ((m & 3) << 10);
        const int kc = m & 7;
        bf16x8 bf[2];
#pragma unroll
        for (int ct = 0; ct < 2; ++ct) {
            int c = (ct << 4) + n16;                    // col 0..31
            int d = q ^ (c & 3);                        // swizzled 16B chunk
            bf[ct] = *(const bf16x8*)(bb + (((c << 2) | d) << 3));
        }
#pragma unroll
        for (int rt = 0; rt < 4; ++rt)
#pragma unroll
            for (int ct = 0; ct < 2; ++ct)
                acc[rt][ct] = __builtin_amdgcn_mfma_f32_16x16x32_bf16(
                    a[rt][kc], bf[ct], acc[rt][ct], 0, 0, 0);
    };
    auto acczero = [&]() {
#pragma unroll
        for (int rt = 0; rt < 4; ++rt)
#pragma unroll
            for (int ct = 0; ct < 2; ++ct) acc[rt][ct] = (f32x4){0.f, 0.f, 0.f, 0.f};
    };
    auto epilogue = [&]() {
#pragma unroll
        for (int rt = 0; rt < 4; ++rt)
#pragma unroll
            for (int ct = 0; ct < 2; ++ct)
#pragma unroll
                for (int r = 0; r < 4; ++r)
                    rs[rt][r] += __builtin_amdgcn_exp2f(acc[rt][ct][r] * TWO_LOG2E);
    };

    stage(0); stage(1); stage(2);

    for (int cc = 0; cc < 15; ++cc) {           // chunks 0..119: always stage+vmcnt(6)
        acczero();
#pragma unroll
        for (int kc = 0; kc < 8; ++kc) {
            int m = (cc << 3) + kc;
            stage(m + 3);
            asm volatile("s_waitcnt vmcnt(6)" ::: "memory");
            consume(m);
        }
        epilogue();
    }
    // peeled tail cc=15: chunks 120..127 (stages for 123..127 then drain 6->4->2->0)
    acczero();
#pragma unroll
    for (int kc = 0; kc < 5; ++kc) {            // m=120..124: stage m+3 (123..127)
        int m = 120 + kc;
        stage(m + 3);
        asm volatile("s_waitcnt vmcnt(6)" ::: "memory");
        consume(m);
    }
    asm volatile("s_waitcnt vmcnt(4)" ::: "memory");
    consume(125);
    asm volatile("s_waitcnt vmcnt(2)" ::: "memory");
    consume(126);
    asm volatile("s_waitcnt vmcnt(0)" ::: "memory");
    consume(127);
    epilogue();

    // flush once per job (C/D layout: col=n16, row=q*4+r)
#pragma unroll
    for (int rt = 0; rt < 4; ++rt)
#pragma unroll
        for (int r = 0; r < 4; ++r) {
            float s = rs[rt][r];
            s += __shfl_xor(s, 1, 64);
            s += __shfl_xor(s, 2, 64);
            s += __shfl_xor(s, 4, 64);
            s += __shfl_xor(s, 8, 64);
            if (n16 == 0) atomicAdd(&S[rowBase + (rt << 4) + (q << 2) + r], s);
        }
}

// ---------------- kernel 3: loss = mean( log(S_i - e^{sim_ii}) - sim_{i,target} ) -------
__global__ void __launch_bounds__(256) finish_kernel(
    const unsigned short* __restrict__ zn, const float* __restrict__ S,
    float* __restrict__ out)
{
    __shared__ float vals[16];
    const int tid = threadIdx.x, lane = tid & 63, wave = tid >> 6;
    const int q = lane >> 4, n16 = lane & 15;
    const int rib = (wave << 2) + q;                // 0..15 rows per block
    const int row = (blockIdx.x << 4) + rib;        // 512 blocks * 16 rows
    const int tar = (row + 4096) & 8191;

    float drr = 0.f, drt = 0.f;
#pragma unroll
    for (int i = 0; i < 4; ++i) {
        int k = (i << 6) + (n16 << 2);
        uint2 ur = *(const uint2*)(zn + (row << 8) + k);
        uint2 ut = *(const uint2*)(zn + (tar << 8) + k);
        float a0 = __uint_as_float(ur.x << 16),  a1 = __uint_as_float(ur.x & 0xFFFF0000u);
        float a2 = __uint_as_float(ur.y << 16),  a3 = __uint_as_float(ur.y & 0xFFFF0000u);
        float b0 = __uint_as_float(ut.x << 16),  b1 = __uint_as_float(ut.x & 0xFFFF0000u);
        float b2 = __uint_as_float(ut.y << 16),  b3 = __uint_as_float(ut.y & 0xFFFF0000u);
        drr += a0 * a0 + a1 * a1 + a2 * a2 + a3 * a3;
        drt += a0 * b0 + a1 * b1 + a2 * b2 + a3 * b3;
    }
#pragma unroll
    for (int m = 1; m <= 8; m <<= 1) {
        drr += __shfl_xor(drr, m, 64);
        drt += __shfl_xor(drt, m, 64);
    }
    if (n16 == 0) {
        float Sv = S[row] - __builtin_amdgcn_exp2f(drr * TWO_LOG2E);  // remove diagonal
        vals[rib] = 0.693147180559945f * __builtin_amdgcn_logf(Sv) - 2.0f * drt;
    }
    __syncthreads();
    if (tid == 0) {
        float s = 0.f;
#pragma unroll
        for (int i = 0; i < 16; ++i) s += vals[i];
        atomicAdd(out, s * (1.0f / 8192.0f));
    }
}

extern "C" void kernel_launch(void* const* d_in, const int* in_sizes, int n_in,
                              void* d_out, int out_size, void* d_ws, size_t ws_size,
                              hipStream_t stream)
{
    const float* z1 = (const float*)d_in[0];
    const float* z2 = (const float*)d_in[1];
    unsigned short* zn = (unsigned short*)d_ws;                              // 4 MB
    float* S = (float*)((char*)d_ws + 8192 * 256 * sizeof(unsigned short));  // 32 KB
    float* out = (float*)d_out;

    normalize_kernel<<<2048, 256, 0, stream>>>(z1, z2, zn, S, out);
    simexp_kernel<<<2048, 64, 0, stream>>>(zn, S);
    finish_kernel<<<512, 256, 0, stream>>>(zn, S, out);
}